// Round 1
// baseline (574.237 us; speedup 1.0000x reference)
//
#include <hip/hip_runtime.h>

// Problem constants (fixed by setup_inputs)
constexpr int B  = 4;
constexpr int C  = 32;
constexpr int H  = 512;
constexpr int Wd = 960;
constexpr int TS = 4;
constexpr int Ht = H / TS;   // 128
constexpr int Wt = Wd / TS;  // 240

// out[b, k*16 + i*4 + j, ht, wt] = sum_c |fea_l[b,c,y,x] - warp(fea_r, disp_k)[b,c,y,x]|
//   y = ht*4 + i, x = wt*4 + j
//   disp_k = ((d + (k-1)) + (i-1.5)*dy) + (j-1.5)*dx   (k = 0,1,2 <-> disp_d = -1,0,+1)
__global__ __launch_bounds__(256) void tile_warping_kernel(
    const float* __restrict__ tp,   // [B,3,Ht,Wt]
    const float* __restrict__ fl,   // [B,C,H,W]
    const float* __restrict__ fr,   // [B,C,H,W]
    float* __restrict__ out)        // [B,48,Ht,Wt]
{
    int idx = blockIdx.x * 256 + threadIdx.x;
    if (idx >= B * H * Wd) return;

    int x = idx % Wd;
    int t = idx / Wd;
    int y = t % H;
    int b = t / H;

    int ht = y >> 2, ii = y & 3;
    int wt = x >> 2, jj = x & 3;

    int tbase = ((b * 3) * Ht + ht) * Wt + wt;
    float dv  = tp[tbase];
    float dxv = tp[tbase + Ht * Wt];
    float dyv = tp[tbase + 2 * Ht * Wt];

    float oi = (float)ii - 1.5f;
    float oj = (float)jj - 1.5f;

    int   a0[3], a1[3];
    float wk[3];
    bool  val[3];
#pragma unroll
    for (int k = 0; k < 3; ++k) {
        // Match reference rounding order: ((d + disp_d) + oi*dy) + oj*dx
        float disp = ((dv + (float)(k - 1)) + oi * dyv) + oj * dxv;
        float xs = (float)x - disp;
        float ff = floorf(xs);
        wk[k] = xs - ff;
        int F = (int)ff;
        int c0 = min(max(F, 0), Wd - 1);
        a0[k] = c0;
        a1[k] = min(c0 + 1, Wd - 1);
        val[k] = (xs >= 0.0f) && (xs <= (float)(Wd - 1));
    }

    const float* flp = fl + ((b * C) * H + y) * Wd + x;
    const float* frp = fr + ((b * C) * H + y) * Wd;

    float sum[3] = {0.0f, 0.0f, 0.0f};
#pragma unroll 4
    for (int c = 0; c < C; ++c) {
        float l = flp[c * (H * Wd)];
        const float* r = frp + c * (H * Wd);
#pragma unroll
        for (int k = 0; k < 3; ++k) {
            float f0 = r[a0[k]];
            float f1 = r[a1[k]];
            float wv = val[k] ? (f0 * (1.0f - wk[k]) + f1 * wk[k]) : 0.0f;
            sum[k] += fabsf(l - wv);
        }
    }

    int obase = ((b * 48) * Ht + ht) * Wt + wt;
#pragma unroll
    for (int k = 0; k < 3; ++k) {
        out[obase + (k * 16 + ii * 4 + jj) * (Ht * Wt)] = sum[k];
    }
}

extern "C" void kernel_launch(void* const* d_in, const int* in_sizes, int n_in,
                              void* d_out, int out_size, void* d_ws, size_t ws_size,
                              hipStream_t stream) {
    const float* tp = (const float*)d_in[0];
    const float* fl = (const float*)d_in[1];
    const float* fr = (const float*)d_in[2];
    float* out = (float*)d_out;

    int total = B * H * Wd;
    int blocks = (total + 255) / 256;
    tile_warping_kernel<<<blocks, 256, 0, stream>>>(tp, fl, fr, out);
}

// Round 2
// 492.698 us; speedup vs baseline: 1.1655x; 1.1655x over previous
//
#include <hip/hip_runtime.h>
#include <cstdint>

#define AS1 __attribute__((address_space(1)))
#define AS3 __attribute__((address_space(3)))

// Problem constants (fixed by setup_inputs)
constexpr int B  = 4;
constexpr int C  = 32;
constexpr int H  = 512;
constexpr int Wd = 960;
constexpr int Ht = H / 4;    // 128
constexpr int Wt = Wd / 4;   // 240
constexpr int HW = H * Wd;

constexpr int BLKX  = 256;        // x-pixels per block
constexpr int XMARG = 56;         // left margin: disp <= 48+1+slant(~1.5) -> taps >= x-52
constexpr int SELEM = BLKX + 64;  // 320 staged floats per channel (covers [x0-56, x0+263])

// out[b, k*16 + i*4 + j, ht, wt] = sum_c |fea_l[b,c,y,x] - warp(fea_r, disp_k)[b,c,y,x]|
__global__ __launch_bounds__(256, 4) void tile_warping_kernel(
    const float* __restrict__ tp,   // [B,3,Ht,Wt]
    const float* __restrict__ fl,   // [B,C,H,W]
    const float* __restrict__ fr,   // [B,C,H,W]
    float* __restrict__ out)        // [B,48,Ht,Wt]
{
    __shared__ float sm[SELEM * C];   // 40960 B -> 4 blocks/CU

    const int lane = threadIdx.x;
    const int x0 = blockIdx.x * BLKX;
    const int y  = blockIdx.y;
    const int b  = blockIdx.z;
    const int xstart = x0 - XMARG;

    // ---- async stage of fea_r row segment, all 32 channels, into LDS ----
    // Linear LDS fill: chunk c covers elements [c*1024, c*1024+1024); each
    // thread supplies 16 B. LDS dest = wave-uniform base + lane*16 matches
    // the linear layout exactly (no padding).
    const float* frrow = fr + ((size_t)b * C * H + y) * Wd;
    #pragma unroll
    for (int chunk = 0; chunk < (SELEM * C) / (BLKX * 4); ++chunk) {   // 10
        int e   = chunk * (BLKX * 4) + lane * 4;   // element index in sm
        int ch  = e / SELEM;
        int off = e - ch * SELEM;
        // Clamp keeps the 16B load in-bounds; clamped slots are never read
        // (left block: o>=56-51; right block: taps <= W-1 -> o<=247).
        int gx  = min(max(xstart + off, 0), Wd - 4);
        const float* gp = frrow + (size_t)ch * HW + gx;
        __builtin_amdgcn_global_load_lds((const AS1 float*)gp,
                                         (AS3 float*)(&sm[e]), 16, 0, 0);
    }
    __syncthreads();

    const int x = x0 + lane;
    if (x < Wd) {
        const int ht = y >> 2, ii = y & 3;
        const int wt = x >> 2, jj = x & 3;

        const int tbase = ((b * 3) * Ht + ht) * Wt + wt;
        const float dv  = tp[tbase];
        const float dxv = tp[tbase + Ht * Wt];
        const float dyv = tp[tbase + 2 * Ht * Wt];

        const float oi = (float)ii - 1.5f;
        const float oj = (float)jj - 1.5f;

        int   o0[3];
        float w[3], w1[3];
        bool  val[3];
        #pragma unroll
        for (int k = 0; k < 3; ++k) {
            // Reference rounding order: ((d + disp_d) + oi*dy) + oj*dx
            float disp = ((dv + (float)(k - 1)) + oi * dyv) + oj * dxv;
            float xs = (float)x - disp;
            float ff = floorf(xs);
            w[k]  = xs - ff;
            w1[k] = 1.0f - w[k];
            int c0 = min(max((int)ff, 0), Wd - 1);
            o0[k]  = c0 - xstart;   // f1 slot o0+1: if c0==W-1 it's garbage but
                                    // w==0 or invalid there, and finite.
            val[k] = (xs >= 0.0f) && (xs <= (float)(Wd - 1));
        }

        const float* flp = fl + ((size_t)b * C * H + y) * Wd + x;

        float s0 = 0.f, s1 = 0.f, s2 = 0.f;
        #pragma unroll 4
        for (int c = 0; c < C; ++c) {
            float l = flp[(size_t)c * HW];
            const float* bp = sm + c * SELEM;
            float f00 = bp[o0[0]], f01 = bp[o0[0] + 1];
            float f10 = bp[o0[1]], f11 = bp[o0[1] + 1];
            float f20 = bp[o0[2]], f21 = bp[o0[2] + 1];
            float wv0 = val[0] ? (f00 * w1[0] + f01 * w[0]) : 0.f;
            float wv1 = val[1] ? (f10 * w1[1] + f11 * w[1]) : 0.f;
            float wv2 = val[2] ? (f20 * w1[2] + f21 * w[2]) : 0.f;
            s0 += fabsf(l - wv0);
            s1 += fabsf(l - wv1);
            s2 += fabsf(l - wv2);
        }

        const int obase = ((b * 48) * Ht + ht) * Wt + wt;
        out[obase + (0 * 16 + ii * 4 + jj) * (Ht * Wt)] = s0;
        out[obase + (1 * 16 + ii * 4 + jj) * (Ht * Wt)] = s1;
        out[obase + (2 * 16 + ii * 4 + jj) * (Ht * Wt)] = s2;
    }
}

extern "C" void kernel_launch(void* const* d_in, const int* in_sizes, int n_in,
                              void* d_out, int out_size, void* d_ws, size_t ws_size,
                              hipStream_t stream) {
    const float* tp = (const float*)d_in[0];
    const float* fl = (const float*)d_in[1];
    const float* fr = (const float*)d_in[2];
    float* out = (float*)d_out;

    dim3 grid((Wd + BLKX - 1) / BLKX, H, B);   // (4, 512, 4)
    tile_warping_kernel<<<grid, 256, 0, stream>>>(tp, fl, fr, out);
}